// Round 1
// baseline (9.375 us; speedup 1.0000x reference)
//
#include <hip/hip_runtime.h>

// Reference semantics (faithful to the degenerate source):
//   M = 250, SQ = 12, N_REGIONS = 10, all region starts = (0,0).
//   intensity = u*u  (u real, so |u|^2 == u^2)
//   S[b] = sum over intensity[b, 0:12, 0:12]
//   values[b, r] = S[b] for all r in 0..9
//   norms[b] = sqrt(10 * S[b]^2)
//   out[b, r] = S[b] / norms[b]
//
// Only the 12x12 top-left patch of each 250x250 slice is ever read:
// 4096 * 144 floats = ~2.4 MB. Launch-overhead bound.

#define MDIM 250
#define SQ 12
#define NREG 10
#define PATCH (SQ * SQ)  // 144

__global__ __launch_bounds__(64) void imaging_layer_kernel(
    const float* __restrict__ u, float* __restrict__ out) {
    const int b = blockIdx.x;
    const int lane = threadIdx.x;  // 0..63, one wave per block

    const float* ub = u + (size_t)b * (MDIM * MDIM);

    float s = 0.0f;
#pragma unroll
    for (int k = 0; k < 3; ++k) {
        const int i = lane + k * 64;  // 0..191, only i < 144 valid
        if (i < PATCH) {
            const int r = i / SQ;
            const int c = i - r * SQ;
            const float x = ub[r * MDIM + c];
            s += x * x;
        }
    }

    // Wave-wide butterfly reduction across all 64 lanes.
#pragma unroll
    for (int off = 32; off > 0; off >>= 1) {
        s += __shfl_xor(s, off, 64);
    }
    // Every lane now holds the full patch sum S.

    const float val = s / sqrtf(10.0f * s * s);

    if (lane < NREG) {
        out[(size_t)b * NREG + lane] = val;
    }
}

extern "C" void kernel_launch(void* const* d_in, const int* in_sizes, int n_in,
                              void* d_out, int out_size, void* d_ws, size_t ws_size,
                              hipStream_t stream) {
    const float* u = (const float*)d_in[0];
    float* out = (float*)d_out;

    const int batch = in_sizes[0] / (MDIM * MDIM);  // 4096

    imaging_layer_kernel<<<batch, 64, 0, stream>>>(u, out);
}